// Round 5
// baseline (154.711 us; speedup 1.0000x reference)
//
#include <hip/hip_runtime.h>
#include <cstdint>

#define B2 2
#define CCH 256
#define HH 64
#define WW 64
#define HWHW 4096
#define KOUT 324

typedef _Float16 half_t;
typedef _Float16 h2 __attribute__((ext_vector_type(2)));

__device__ __forceinline__ float fdot2f(h2 a, h2 b, float c) {
#if __has_builtin(__builtin_amdgcn_fdot2)
  return __builtin_amdgcn_fdot2(a, b, c, false);
#else
  return c + (float)a.x * (float)b.x + (float)a.y * (float)b.y;
#endif
}

// ---------------------------------------------------------------------------
// (B,C,H,W) fp32 -> (B,HW,C) f16 channel-last. z<2: fmap1 (scaled 1/16),
// z>=2: fmap2. grid (HW/32, C/32, 4), block (32,8).
// ---------------------------------------------------------------------------
__global__ __launch_bounds__(256) void transpose_cl(
    const float* __restrict__ f1, const float* __restrict__ f2,
    half_t* __restrict__ f1t, half_t* __restrict__ f2t) {
  __shared__ float tile[32][33];
  int zz = blockIdx.z;
  const float* src = (zz < 2) ? f1 : f2;
  half_t* dst = (zz < 2) ? f1t : f2t;
  float s = (zz < 2) ? 0.0625f : 1.0f;   // fold 1/sqrt(256) into fmap1
  int b = zz & 1;
  int hw0 = blockIdx.x * 32;
  int c0 = blockIdx.y * 32;
  int tx = threadIdx.x;
  int ty = threadIdx.y;
  const float* sb = src + (size_t)b * CCH * HWHW;
  half_t* db = dst + (size_t)b * HWHW * CCH;
#pragma unroll
  for (int i = 0; i < 4; i++)
    tile[ty + i * 8][tx] = sb[(size_t)(c0 + ty + i * 8) * HWHW + hw0 + tx];
  __syncthreads();
#pragma unroll
  for (int i = 0; i < 4; i++)
    db[(size_t)(hw0 + ty + i * 8) * CCH + c0 + tx] = (half_t)(tile[tx][ty + i * 8] * s);
}

// ---------------------------------------------------------------------------
// Pyramid levels 1..3 from level 0 (2^L x 2^L mean), f16 in/out, fp32 accum.
// ---------------------------------------------------------------------------
__global__ __launch_bounds__(256) void pool_all(
    const h2* __restrict__ l0, h2* __restrict__ l1,
    h2* __restrict__ l2, h2* __restrict__ l3) {
  int idx = blockIdx.x * blockDim.x + threadIdx.x;
  const int n1 = B2 * 32 * 32 * 128;
  const int n2 = B2 * 16 * 16 * 128;
  const int n3 = B2 * 8 * 8 * 128;
  int L, Wo, local;
  h2* dst;
  if (idx < n1) { L = 1; Wo = 32; local = idx; dst = l1; }
  else if (idx < n1 + n2) { L = 2; Wo = 16; local = idx - n1; dst = l2; }
  else if (idx < n1 + n2 + n3) { L = 3; Wo = 8; local = idx - n1 - n2; dst = l3; }
  else return;
  int f = 1 << L;
  int sh = 6 - L;
  int c2 = local & 127;
  int t = local >> 7;
  int x = t & (Wo - 1);
  int y = (t >> sh) & (Wo - 1);
  int b = t >> (2 * sh);
  const h2* src = l0 + (size_t)b * HWHW * 128 + c2;
  float ax = 0.f, ay = 0.f;
  for (int dy = 0; dy < f; dy++)
    for (int dx = 0; dx < f; dx++) {
      h2 a = src[(size_t)((y * f + dy) * WW + (x * f + dx)) * 128];
      ax += (float)a.x; ay += (float)a.y;
    }
  float s = 1.0f / (float)(f * f);
  h2 r;
  r.x = (half_t)(ax * s);
  r.y = (half_t)(ay * s);
  dst[local] = r;
}

// ---------------------------------------------------------------------------
// 16-lane sum via DPP (pure VALU): quad xor1, quad xor2, row_half_mirror,
// row_mirror. All 16 lanes end with the group total.
// ---------------------------------------------------------------------------
__device__ __forceinline__ float dpp_sum16(float x) {
  int v;
  v = __builtin_amdgcn_update_dpp(0, __float_as_int(x), 0xB1, 0xF, 0xF, true);
  x += __int_as_float(v);
  v = __builtin_amdgcn_update_dpp(0, __float_as_int(x), 0x4E, 0xF, 0xF, true);
  x += __int_as_float(v);
  v = __builtin_amdgcn_update_dpp(0, __float_as_int(x), 0x141, 0xF, 0xF, true);
  x += __int_as_float(v);
  v = __builtin_amdgcn_update_dpp(0, __float_as_int(x), 0x140, 0xF, 0xF, true);
  x += __int_as_float(v);
  return x;
}

// ---------------------------------------------------------------------------
// sample16: one block = 16 consecutive queries (one 16-px row chunk, 16-aligned)
// x 8 waves. Wave w: level l = w>>1, half h = w&1 handles queries h*8..h*8+7.
// Level-3 batch image (32 KB) staged in LDS; levels 0-2 stream from L2.
// 4 taps in flight per wave (lane>>4), 16 lanes/tap, 16 ch/lane, fdot2.
// Epilogue writes final (B,324,H,W) directly: lanes 0-15 = q=0..15 -> 64B lines.
// ---------------------------------------------------------------------------
__global__ __launch_bounds__(512, 4) void sample16(
    const float* __restrict__ coords,
    const half_t* __restrict__ f1t,
    const half_t* __restrict__ f2l0, const half_t* __restrict__ f2l1,
    const half_t* __restrict__ f2l2, const half_t* __restrict__ f2l3,
    float* __restrict__ out) {
  __shared__ float4 f1s4[512];       // 8 KB : 16 queries x 256ch f16 (pre-scaled)
  __shared__ float4 l3img[2048];     // 32 KB: this batch's full level-3 image
  __shared__ float P[4][16][100];    // 25.6 KB
  __shared__ float wgt[4][16][4];    // wx0, wx1, wy0, wy1
  __shared__ float cxy[2][16];

  int bid = blockIdx.x;
  int g = ((bid & 7) << 6) | (bid >> 3);   // XCD-contiguous groups (512 % 8 == 0)
  int n0 = g << 4;
  int b = n0 >> 12;
  int i0 = n0 & 4095;
  int yi = i0 >> 6;
  int x0 = i0 & 63;                        // multiple of 16
  int tid = threadIdx.x;

  f1s4[tid] = ((const float4*)(f1t + (size_t)n0 * CCH))[tid];
  {
    const float4* l3g = (const float4*)(f2l3 + (size_t)b * 64 * CCH);
#pragma unroll
    for (int r = 0; r < 4; r++) l3img[tid + r * 512] = l3g[tid + r * 512];
  }
  if (tid < 32) {
    int q = tid & 15, c = tid >> 4;
    cxy[c][q] = coords[(size_t)(b * 2 + c) * HWHW + i0 + q];
  }
  __syncthreads();

  int w = tid >> 6;
  int l = w >> 1;     // level
  int h = w & 1;      // query-half
  int lane = tid & 63;
  int lg = lane >> 4;
  int l16 = lane & 15;

  float inv = 1.0f / (float)(1 << l);
  int Hl = HH >> l, Wl = WW >> l;
  const half_t* f2 = (l == 0) ? f2l0 : (l == 1) ? f2l1 : f2l2;  // l==3 uses LDS
  const float4* f2b = (const float4*)(f2) + (size_t)b * Hl * Wl * 32 + l16;
  const float4* l3b = l3img + l16;
  const h2* f1h = (const h2*)f1s4;

  for (int qq = 0; qq < 8; qq++) {
    int q = h * 8 + qq;
    float clx = cxy[0][q], cly = cxy[1][q];
    float xl = clx * inv, yl = cly * inv;
    float fx = floorf(xl), fy = floorf(yl);
    int ix0 = (int)fx - 4, iy0 = (int)fy - 4;
    float wx1 = xl - fx, wy1 = yl - fy;
    if (lane == 0) {
      wgt[l][q][0] = 1.0f - wx1; wgt[l][q][1] = wx1;
      wgt[l][q][2] = 1.0f - wy1; wgt[l][q][3] = wy1;
    }
    int fi = q * 128 + l16 * 4;
    h2 fa0 = f1h[fi + 0], fa1 = f1h[fi + 1], fa2 = f1h[fi + 2], fa3 = f1h[fi + 3];
    h2 fb0 = f1h[fi + 64], fb1 = f1h[fi + 65], fb2 = f1h[fi + 66], fb3 = f1h[fi + 67];

    int u = 0, v = lg, t = lg;
    if (l == 3) {
      for (int it = 0; it < 25; it++) {
        int txp = ix0 + u, typ = iy0 + v;
        bool inb = ((unsigned)txp < (unsigned)Wl) & ((unsigned)typ < (unsigned)Hl);
        float d = 0.0f;
        if (inb) {
          const float4* tp = l3b + (size_t)(typ * 8 + txp) * 32;
          float4 A = tp[0];
          float4 Bv = tp[16];
          const h2* ah = (const h2*)&A;
          const h2* bh = (const h2*)&Bv;
          d = fdot2f(ah[0], fa0, d); d = fdot2f(ah[1], fa1, d);
          d = fdot2f(ah[2], fa2, d); d = fdot2f(ah[3], fa3, d);
          d = fdot2f(bh[0], fb0, d); d = fdot2f(bh[1], fb1, d);
          d = fdot2f(bh[2], fb2, d); d = fdot2f(bh[3], fb3, d);
        }
        d = dpp_sum16(d);
        if (l16 == 0) P[l][q][t] = d;
        t += 4; v += 4;
        bool wrap = v >= 10;
        v = wrap ? v - 10 : v;
        u = wrap ? u + 1 : u;
      }
    } else {
      for (int it = 0; it < 25; it++) {
        int txp = ix0 + u, typ = iy0 + v;
        bool inb = ((unsigned)txp < (unsigned)Wl) & ((unsigned)typ < (unsigned)Hl);
        float d = 0.0f;
        if (inb) {
          const float4* tp = f2b + (size_t)(typ * Wl + txp) * 32;
          float4 A = tp[0];
          float4 Bv = tp[16];
          const h2* ah = (const h2*)&A;
          const h2* bh = (const h2*)&Bv;
          d = fdot2f(ah[0], fa0, d); d = fdot2f(ah[1], fa1, d);
          d = fdot2f(ah[2], fa2, d); d = fdot2f(ah[3], fa3, d);
          d = fdot2f(bh[0], fb0, d); d = fdot2f(bh[1], fb1, d);
          d = fdot2f(bh[2], fb2, d); d = fdot2f(bh[3], fb3, d);
        }
        d = dpp_sum16(d);
        if (l16 == 0) P[l][q][t] = d;
        t += 4; v += 4;
        bool wrap = v >= 10;
        v = wrap ? v - 10 : v;
        u = wrap ? u + 1 : u;
      }
    }
  }
  __syncthreads();

  // epilogue: wave (l,h) covers k = h*41 .. h*41+(41-h)-1 for all 16 queries.
  // lanes 0-15 = q0..15 of one k -> one full 64B line per 16-lane group.
  int limit = h ? 40 : 41;
#pragma unroll
  for (int kk = 0; kk < 11; kk++) {
    int idx = kk * 64 + lane;
    int kl = idx >> 4;
    int q = idx & 15;
    if (kl < limit) {
      int k = h * 41 + kl;
      int a = k / 9, bb2 = k - a * 9;
      float wx0 = wgt[l][q][0], wx1 = wgt[l][q][1];
      float wy0 = wgt[l][q][2], wy1 = wgt[l][q][3];
      const float* Pq = P[l][q];
      float val = wy0 * (wx0 * Pq[a * 10 + bb2] + wx1 * Pq[(a + 1) * 10 + bb2])
                + wy1 * (wx0 * Pq[a * 10 + bb2 + 1] + wx1 * Pq[(a + 1) * 10 + bb2 + 1]);
      out[(size_t)(b * KOUT + l * 81 + k) * HWHW + (size_t)yi * WW + x0 + q] = val;
    }
  }
}

// ---------------------------------------------------------------------------
extern "C" void kernel_launch(void* const* d_in, const int* in_sizes, int n_in,
                              void* d_out, int out_size, void* d_ws, size_t ws_size,
                              hipStream_t stream) {
  const float* fmap1 = (const float*)d_in[0];
  const float* fmap2 = (const float*)d_in[1];
  const float* coords = (const float*)d_in[2];
  float* out = (float*)d_out;

  char* ws = (char*)d_ws;
  half_t* f1t  = (half_t*)(ws);                        // 4 MB   (B,HW,C) f16, pre-scaled
  half_t* f2l0 = (half_t*)(ws + ((size_t)4 << 20));    // 4 MB   (B,64,64,C) f16
  half_t* f2l1 = (half_t*)(ws + ((size_t)8 << 20));    // 1 MB   (B,32,32,C) f16
  half_t* f2l2 = (half_t*)(ws + ((size_t)9 << 20));    // 256 KB (B,16,16,C) f16
  half_t* f2l3 = (half_t*)(ws + ((size_t)9 << 20) + ((size_t)512 << 10)); // 64 KB

  dim3 tb(32, 8, 1);
  dim3 tg(HWHW / 32, CCH / 32, 4);
  transpose_cl<<<tg, tb, 0, stream>>>(fmap1, fmap2, f1t, f2l0);

  int npool = B2 * (32 * 32 + 16 * 16 + 8 * 8) * 128;
  pool_all<<<(npool + 255) / 256, 256, 0, stream>>>(
      (const h2*)f2l0, (h2*)f2l1, (h2*)f2l2, (h2*)f2l3);

  sample16<<<512, 512, 0, stream>>>(coords, f1t, f2l0, f2l1, f2l2, f2l3, out);
}

// Round 6
// 147.844 us; speedup vs baseline: 1.0464x; 1.0464x over previous
//
#include <hip/hip_runtime.h>
#include <cstdint>

#define B2 2
#define CCH 256
#define HH 64
#define WW 64
#define HWHW 4096
#define KOUT 324

typedef _Float16 half_t;
typedef _Float16 h2 __attribute__((ext_vector_type(2)));
typedef _Float16 h8 __attribute__((ext_vector_type(8)));
typedef float f32x4 __attribute__((ext_vector_type(4)));

__device__ __forceinline__ float fdot2f(h2 a, h2 b, float c) {
#if __has_builtin(__builtin_amdgcn_fdot2)
  return __builtin_amdgcn_fdot2(a, b, c, false);
#else
  return c + (float)a.x * (float)b.x + (float)a.y * (float)b.y;
#endif
}

// ---------------------------------------------------------------------------
// (B,C,H,W) fp32 -> (B,HW,C) f16 channel-last. z<2: fmap1 (scaled 1/16),
// z>=2: fmap2. grid (HW/32, C/32, 4), block (32,8).
// ---------------------------------------------------------------------------
__global__ __launch_bounds__(256) void transpose_cl(
    const float* __restrict__ f1, const float* __restrict__ f2,
    half_t* __restrict__ f1t, half_t* __restrict__ f2t) {
  __shared__ float tile[32][33];
  int zz = blockIdx.z;
  const float* src = (zz < 2) ? f1 : f2;
  half_t* dst = (zz < 2) ? f1t : f2t;
  float s = (zz < 2) ? 0.0625f : 1.0f;   // fold 1/sqrt(256) into fmap1
  int b = zz & 1;
  int hw0 = blockIdx.x * 32;
  int c0 = blockIdx.y * 32;
  int tx = threadIdx.x;
  int ty = threadIdx.y;
  const float* sb = src + (size_t)b * CCH * HWHW;
  half_t* db = dst + (size_t)b * HWHW * CCH;
#pragma unroll
  for (int i = 0; i < 4; i++)
    tile[ty + i * 8][tx] = sb[(size_t)(c0 + ty + i * 8) * HWHW + hw0 + tx];
  __syncthreads();
#pragma unroll
  for (int i = 0; i < 4; i++)
    db[(size_t)(hw0 + ty + i * 8) * CCH + c0 + tx] = (half_t)(tile[tx][ty + i * 8] * s);
}

// ---------------------------------------------------------------------------
// Pyramid levels 1..3 from level 0 (2^L x 2^L mean), f16 in/out, fp32 accum.
// ---------------------------------------------------------------------------
__global__ __launch_bounds__(256) void pool_all(
    const h2* __restrict__ l0, h2* __restrict__ l1,
    h2* __restrict__ l2, h2* __restrict__ l3) {
  int idx = blockIdx.x * blockDim.x + threadIdx.x;
  const int n1 = B2 * 32 * 32 * 128;
  const int n2 = B2 * 16 * 16 * 128;
  const int n3 = B2 * 8 * 8 * 128;
  int L, Wo, local;
  h2* dst;
  if (idx < n1) { L = 1; Wo = 32; local = idx; dst = l1; }
  else if (idx < n1 + n2) { L = 2; Wo = 16; local = idx - n1; dst = l2; }
  else if (idx < n1 + n2 + n3) { L = 3; Wo = 8; local = idx - n1 - n2; dst = l3; }
  else return;
  int f = 1 << L;
  int sh = 6 - L;
  int c2 = local & 127;
  int t = local >> 7;
  int x = t & (Wo - 1);
  int y = (t >> sh) & (Wo - 1);
  int b = t >> (2 * sh);
  const h2* src = l0 + (size_t)b * HWHW * 128 + c2;
  float ax = 0.f, ay = 0.f;
  for (int dy = 0; dy < f; dy++)
    for (int dx = 0; dx < f; dx++) {
      h2 a = src[(size_t)((y * f + dy) * WW + (x * f + dx)) * 128];
      ax += (float)a.x; ay += (float)a.y;
    }
  float s = 1.0f / (float)(f * f);
  h2 r;
  r.x = (half_t)(ax * s);
  r.y = (half_t)(ay * s);
  dst[local] = r;
}

// ---------------------------------------------------------------------------
// corr23: materialize FULL level-2 (16x16) and level-3 (8x8) correlation
// fields for every query via MFMA. Block = 16 queries, 4 waves; wave w does
// tap-tiles w*5..w*5+4 (20 tiles of 16 taps = 256 l2 + 64 l3).
// A (16 queries x 256 ch, f16 pre-scaled) in regs; B streamed from L2.
// D written fp32 to corr[n][320] (p<256: l2 tap y*16+x; p>=256: l3 y*8+x).
// ---------------------------------------------------------------------------
__global__ __launch_bounds__(256) void corr23_k(
    const half_t* __restrict__ f1t,
    const half_t* __restrict__ f2l2, const half_t* __restrict__ f2l3,
    float* __restrict__ corr) {
  int bid = blockIdx.x;
  int g = ((bid & 7) << 6) | (bid >> 3);   // XCD swizzle (512 blocks)
  int n0 = g << 4;
  int b = n0 >> 12;
  int w = threadIdx.x >> 6;
  int l = threadIdx.x & 63;
  int row = l & 15;       // A: query row ; B: tap col ; D: tap col
  int kg = l >> 4;        // k-group (8 ch each)

  // A fragments: a[ks] = f1[(n0+row)][ks*32 + kg*8 .. +7]
  const h8* A = (const h8*)(f1t + ((size_t)(n0 + row) * CCH) + kg * 8);
  h8 a[8];
#pragma unroll
  for (int ks = 0; ks < 8; ks++) a[ks] = A[ks * 4];

  for (int nt = w * 5; nt < w * 5 + 5; nt++) {
    const half_t* Bb = (nt < 16)
        ? f2l2 + ((size_t)b * 256 + nt * 16) * CCH
        : f2l3 + ((size_t)b * 64 + (nt - 16) * 16) * CCH;
    const h8* Bp = (const h8*)(Bb + (size_t)row * CCH + kg * 8);
    f32x4 acc = {0.f, 0.f, 0.f, 0.f};
#pragma unroll
    for (int ks = 0; ks < 8; ks++)
      acc = __builtin_amdgcn_mfma_f32_16x16x32_f16(a[ks], Bp[ks * 4], acc, 0, 0, 0);
#pragma unroll
    for (int r = 0; r < 4; r++) {
      int q = kg * 4 + r;   // D row = query
      corr[(size_t)(n0 + q) * 320 + nt * 16 + row] = acc[r];
    }
  }
}

// ---------------------------------------------------------------------------
// 16-lane sum via DPP (pure VALU): quad xor1, quad xor2, row_half_mirror,
// row_mirror. All 16 lanes end with the group total.
// ---------------------------------------------------------------------------
__device__ __forceinline__ float dpp_sum16(float x) {
  int v;
  v = __builtin_amdgcn_update_dpp(0, __float_as_int(x), 0xB1, 0xF, 0xF, true);
  x += __int_as_float(v);
  v = __builtin_amdgcn_update_dpp(0, __float_as_int(x), 0x4E, 0xF, 0xF, true);
  x += __int_as_float(v);
  v = __builtin_amdgcn_update_dpp(0, __float_as_int(x), 0x141, 0xF, 0xF, true);
  x += __int_as_float(v);
  v = __builtin_amdgcn_update_dpp(0, __float_as_int(x), 0x140, 0xF, 0xF, true);
  x += __int_as_float(v);
  return x;
}

// ---------------------------------------------------------------------------
// sample16b: block = 16 consecutive queries (x0 16-aligned), 8 waves.
// Wave w: level l = w>>2 (0 or 1), queries (w&3)*4 .. +3; 100-tap streaming
// dots as in r4 (4 taps in flight, 16 lanes/tap, fdot2, DPP reduce).
// Levels 2/3 come from the corr23 field via 4-point bilinear gathers.
// Output written directly in (B,324,H,W): 16 lanes = 16 queries -> 64B lines.
// ---------------------------------------------------------------------------
__global__ __launch_bounds__(512, 4) void sample16b(
    const float* __restrict__ coords,
    const half_t* __restrict__ f1t,
    const half_t* __restrict__ f2l0, const half_t* __restrict__ f2l1,
    const float* __restrict__ corr,
    float* __restrict__ out) {
  __shared__ float4 f1s4[512];       // 8 KB : 16 queries x 256ch f16 (pre-scaled)
  __shared__ float P[2][16][100];    // 12.8 KB (levels 0,1 only)
  __shared__ float wgt[2][16][4];    // wx0, wx1, wy0, wy1
  __shared__ float cxy[2][16];

  int bid = blockIdx.x;
  int g = ((bid & 7) << 6) | (bid >> 3);   // XCD-contiguous groups (512 blocks)
  int n0 = g << 4;
  int b = n0 >> 12;
  int i0 = n0 & 4095;
  int yi = i0 >> 6;
  int x0 = i0 & 63;
  int tid = threadIdx.x;

  f1s4[tid] = ((const float4*)(f1t + (size_t)n0 * CCH))[tid];
  if (tid < 32) {
    int q = tid & 15, c = tid >> 4;
    cxy[c][q] = coords[(size_t)(b * 2 + c) * HWHW + i0 + q];
  }
  __syncthreads();

  int w = tid >> 6;
  int l = w >> 2;            // level 0 or 1
  int lane = tid & 63;
  int lg = lane >> 4;
  int l16 = lane & 15;

  float inv = (l == 0) ? 1.0f : 0.5f;
  int Hl = HH >> l, Wl = WW >> l;
  const half_t* f2 = (l == 0) ? f2l0 : f2l1;
  const float4* f2b = (const float4*)(f2) + (size_t)b * Hl * Wl * 32 + l16;
  const h2* f1h = (const h2*)f1s4;

  for (int qq = 0; qq < 4; qq++) {
    int q = (w & 3) * 4 + qq;
    float clx = cxy[0][q], cly = cxy[1][q];
    float xl = clx * inv, yl = cly * inv;
    float fx = floorf(xl), fy = floorf(yl);
    int ix0 = (int)fx - 4, iy0 = (int)fy - 4;
    float wx1 = xl - fx, wy1 = yl - fy;
    if (lane == 0) {
      wgt[l][q][0] = 1.0f - wx1; wgt[l][q][1] = wx1;
      wgt[l][q][2] = 1.0f - wy1; wgt[l][q][3] = wy1;
    }
    int fi = q * 128 + l16 * 4;
    h2 fa0 = f1h[fi + 0], fa1 = f1h[fi + 1], fa2 = f1h[fi + 2], fa3 = f1h[fi + 3];
    h2 fb0 = f1h[fi + 64], fb1 = f1h[fi + 65], fb2 = f1h[fi + 66], fb3 = f1h[fi + 67];

    int u = 0, v = lg, t = lg;
    for (int it = 0; it < 25; it++) {
      int txp = ix0 + u, typ = iy0 + v;
      bool inb = ((unsigned)txp < (unsigned)Wl) & ((unsigned)typ < (unsigned)Hl);
      float d = 0.0f;
      if (inb) {
        const float4* tp = f2b + (size_t)(typ * Wl + txp) * 32;
        float4 A = tp[0];
        float4 Bv = tp[16];
        const h2* ah = (const h2*)&A;
        const h2* bh = (const h2*)&Bv;
        d = fdot2f(ah[0], fa0, d); d = fdot2f(ah[1], fa1, d);
        d = fdot2f(ah[2], fa2, d); d = fdot2f(ah[3], fa3, d);
        d = fdot2f(bh[0], fb0, d); d = fdot2f(bh[1], fb1, d);
        d = fdot2f(bh[2], fb2, d); d = fdot2f(bh[3], fb3, d);
      }
      d = dpp_sum16(d);
      if (l16 == 0) P[l][q][t] = d;
      t += 4; v += 4;
      bool wrap = v >= 10;
      v = wrap ? v - 10 : v;
      u = wrap ? u + 1 : u;
    }
  }
  __syncthreads();

  // ---- epilogue A: levels 0,1 from P (2 x 81 x 16 outputs) ----
#pragma unroll
  for (int it = 0; it < 6; it++) {
    int kidx = it * 32 + (tid >> 4);
    if (kidx < 162) {
      int lvl = kidx >= 81;
      int k = kidx - 81 * lvl;
      int q = tid & 15;
      int a = k / 9, bb2 = k - a * 9;
      float wx0 = wgt[lvl][q][0], wx1 = wgt[lvl][q][1];
      float wy0 = wgt[lvl][q][2], wy1 = wgt[lvl][q][3];
      const float* Pq = P[lvl][q];
      float val = wy0 * (wx0 * Pq[a * 10 + bb2] + wx1 * Pq[(a + 1) * 10 + bb2])
                + wy1 * (wx0 * Pq[a * 10 + bb2 + 1] + wx1 * Pq[(a + 1) * 10 + bb2 + 1]);
      out[(size_t)(b * KOUT + lvl * 81 + k) * HWHW + (size_t)yi * WW + x0 + q] = val;
    }
  }

  // ---- epilogue B: levels 2,3 via 4-point gathers from corr23 field ----
#pragma unroll
  for (int it = 0; it < 6; it++) {
    int kidx = it * 32 + (tid >> 4);
    if (kidx < 162) {
      int lvl = 2 + (kidx >= 81);
      int k = kidx - 81 * (kidx >= 81);
      int q = tid & 15;
      float inv2 = (lvl == 2) ? 0.25f : 0.125f;
      int Wl2 = (lvl == 2) ? 16 : 8;
      int base = (lvl == 2) ? 0 : 256;
      float xl = cxy[0][q] * inv2, yl = cxy[1][q] * inv2;
      float fx = floorf(xl), fy = floorf(yl);
      int ix0 = (int)fx - 4, iy0 = (int)fy - 4;
      float wx1 = xl - fx, wx0 = 1.0f - wx1;
      float wy1 = yl - fy, wy0 = 1.0f - wy1;
      const float* cq = corr + (size_t)(n0 + q) * 320 + base;
      int a = k / 9, bb2 = k - a * 9;
      float p00 = 0.f, p10 = 0.f, p01 = 0.f, p11 = 0.f;
      {
        int x = ix0 + a, y = iy0 + bb2;
        if (((unsigned)x < (unsigned)Wl2) & ((unsigned)y < (unsigned)Wl2)) p00 = cq[y * Wl2 + x];
      }
      {
        int x = ix0 + a + 1, y = iy0 + bb2;
        if (((unsigned)x < (unsigned)Wl2) & ((unsigned)y < (unsigned)Wl2)) p10 = cq[y * Wl2 + x];
      }
      {
        int x = ix0 + a, y = iy0 + bb2 + 1;
        if (((unsigned)x < (unsigned)Wl2) & ((unsigned)y < (unsigned)Wl2)) p01 = cq[y * Wl2 + x];
      }
      {
        int x = ix0 + a + 1, y = iy0 + bb2 + 1;
        if (((unsigned)x < (unsigned)Wl2) & ((unsigned)y < (unsigned)Wl2)) p11 = cq[y * Wl2 + x];
      }
      float val = wy0 * (wx0 * p00 + wx1 * p10) + wy1 * (wx0 * p01 + wx1 * p11);
      out[(size_t)(b * KOUT + lvl * 81 + k) * HWHW + (size_t)yi * WW + x0 + q] = val;
    }
  }
}

// ---------------------------------------------------------------------------
extern "C" void kernel_launch(void* const* d_in, const int* in_sizes, int n_in,
                              void* d_out, int out_size, void* d_ws, size_t ws_size,
                              hipStream_t stream) {
  const float* fmap1 = (const float*)d_in[0];
  const float* fmap2 = (const float*)d_in[1];
  const float* coords = (const float*)d_in[2];
  float* out = (float*)d_out;

  char* ws = (char*)d_ws;
  half_t* f1t  = (half_t*)(ws);                        // 4 MB   (B,HW,C) f16, pre-scaled
  half_t* f2l0 = (half_t*)(ws + ((size_t)4 << 20));    // 4 MB   (B,64,64,C) f16
  half_t* f2l1 = (half_t*)(ws + ((size_t)8 << 20));    // 1 MB   (B,32,32,C) f16
  half_t* f2l2 = (half_t*)(ws + ((size_t)9 << 20));    // 256 KB (B,16,16,C) f16
  half_t* f2l3 = (half_t*)(ws + ((size_t)9 << 20) + ((size_t)512 << 10)); // 64 KB
  float*  corr = (float*)(ws + ((size_t)10 << 20));    // 10.5 MB (B*HW, 320) fp32

  dim3 tb(32, 8, 1);
  dim3 tg(HWHW / 32, CCH / 32, 4);
  transpose_cl<<<tg, tb, 0, stream>>>(fmap1, fmap2, f1t, f2l0);

  int npool = B2 * (32 * 32 + 16 * 16 + 8 * 8) * 128;
  pool_all<<<(npool + 255) / 256, 256, 0, stream>>>(
      (const h2*)f2l0, (h2*)f2l1, (h2*)f2l2, (h2*)f2l3);

  corr23_k<<<512, 256, 0, stream>>>(f1t, f2l2, f2l3, corr);

  sample16b<<<512, 512, 0, stream>>>(coords, f1t, f2l0, f2l1, corr, out);
}

// Round 7
// 145.427 us; speedup vs baseline: 1.0638x; 1.0166x over previous
//
#include <hip/hip_runtime.h>
#include <cstdint>

#define B2 2
#define CCH 256
#define HH 64
#define WW 64
#define HWHW 4096
#define KOUT 324

typedef _Float16 half_t;
typedef _Float16 h2 __attribute__((ext_vector_type(2)));
typedef _Float16 h8 __attribute__((ext_vector_type(8)));
typedef float f32x4 __attribute__((ext_vector_type(4)));

// padded level-0 (96x96, origin 16,16) and level-1 (64x64, origin 16,16)
#define P0 96
#define P1 64

__device__ __forceinline__ float fdot2f(h2 a, h2 b, float c) {
#if __has_builtin(__builtin_amdgcn_fdot2)
  return __builtin_amdgcn_fdot2(a, b, c, false);
#else
  return c + (float)a.x * (float)b.x + (float)a.y * (float)b.y;
#endif
}

// ---------------------------------------------------------------------------
// zero the padded l0/l1 buffers (they are contiguous in ws). 13.6 MB.
// ---------------------------------------------------------------------------
__global__ __launch_bounds__(256) void zero_pads(float4* __restrict__ p, int n) {
  int i = blockIdx.x * 256 + threadIdx.x;
  if (i < n) p[i] = make_float4(0.f, 0.f, 0.f, 0.f);
}

// ---------------------------------------------------------------------------
// (B,C,H,W) fp32 -> channel-last f16. z<2: fmap1 -> f1t (B,HW,C), scaled 1/16.
// z>=2: fmap2 -> f2l0p (B,96,96,C) padded, origin (16,16).
// ---------------------------------------------------------------------------
__global__ __launch_bounds__(256) void transpose_cl(
    const float* __restrict__ f1, const float* __restrict__ f2,
    half_t* __restrict__ f1t, half_t* __restrict__ f2l0p) {
  __shared__ float tile[32][33];
  int zz = blockIdx.z;
  const float* src = (zz < 2) ? f1 : f2;
  float s = (zz < 2) ? 0.0625f : 1.0f;
  int b = zz & 1;
  int hw0 = blockIdx.x * 32;
  int c0 = blockIdx.y * 32;
  int tx = threadIdx.x;
  int ty = threadIdx.y;
  const float* sb = src + (size_t)b * CCH * HWHW;
#pragma unroll
  for (int i = 0; i < 4; i++)
    tile[ty + i * 8][tx] = sb[(size_t)(c0 + ty + i * 8) * HWHW + hw0 + tx];
  __syncthreads();
  if (zz < 2) {
    half_t* db = f1t + (size_t)b * HWHW * CCH;
#pragma unroll
    for (int i = 0; i < 4; i++)
      db[(size_t)(hw0 + ty + i * 8) * CCH + c0 + tx] = (half_t)(tile[tx][ty + i * 8] * s);
  } else {
    half_t* db = f2l0p + (size_t)b * P0 * P0 * CCH;
#pragma unroll
    for (int i = 0; i < 4; i++) {
      int hw = hw0 + ty + i * 8;
      int y = hw >> 6, x = hw & 63;
      db[(size_t)((y + 16) * P0 + (x + 16)) * CCH + c0 + tx] = (half_t)tile[tx][ty + i * 8];
    }
  }
}

// ---------------------------------------------------------------------------
// Pyramid levels 1..3 from padded level 0. l1 written padded (64x64 origin
// 16,16); l2 (16x16), l3 (8x8) unpadded. f16 in/out, fp32 accum.
// ---------------------------------------------------------------------------
__global__ __launch_bounds__(256) void pool_all(
    const h2* __restrict__ l0p, h2* __restrict__ l1p,
    h2* __restrict__ l2, h2* __restrict__ l3) {
  int idx = blockIdx.x * blockDim.x + threadIdx.x;
  const int n1 = B2 * 32 * 32 * 128;
  const int n2 = B2 * 16 * 16 * 128;
  const int n3 = B2 * 8 * 8 * 128;
  int L, Wo, local;
  if (idx < n1) { L = 1; Wo = 32; local = idx; }
  else if (idx < n1 + n2) { L = 2; Wo = 16; local = idx - n1; }
  else if (idx < n1 + n2 + n3) { L = 3; Wo = 8; local = idx - n1 - n2; }
  else return;
  int f = 1 << L;
  int sh = 6 - L;
  int c2 = local & 127;
  int t = local >> 7;
  int x = t & (Wo - 1);
  int y = (t >> sh) & (Wo - 1);
  int b = t >> (2 * sh);
  const h2* src = l0p + (size_t)b * P0 * P0 * 128 + c2;
  float ax = 0.f, ay = 0.f;
  for (int dy = 0; dy < f; dy++)
    for (int dx = 0; dx < f; dx++) {
      h2 a = src[(size_t)((y * f + dy + 16) * P0 + (x * f + dx + 16)) * 128];
      ax += (float)a.x; ay += (float)a.y;
    }
  float s = 1.0f / (float)(f * f);
  h2 r;
  r.x = (half_t)(ax * s);
  r.y = (half_t)(ay * s);
  if (L == 1)
    l1p[((size_t)b * P1 * P1 + (size_t)(y + 16) * P1 + (x + 16)) * 128 + c2] = r;
  else if (L == 2)
    l2[local] = r;
  else
    l3[local] = r;
}

// ---------------------------------------------------------------------------
// corr23: full level-2 (16x16) + level-3 (8x8) correlation fields via MFMA.
// Block = 16 queries, 4 waves; wave w does tap-tiles w*5..w*5+4.
// ---------------------------------------------------------------------------
__global__ __launch_bounds__(256) void corr23_k(
    const half_t* __restrict__ f1t,
    const half_t* __restrict__ f2l2, const half_t* __restrict__ f2l3,
    float* __restrict__ corr) {
  int bid = blockIdx.x;
  int g = ((bid & 7) << 6) | (bid >> 3);   // XCD swizzle (512 blocks)
  int n0 = g << 4;
  int b = n0 >> 12;
  int w = threadIdx.x >> 6;
  int l = threadIdx.x & 63;
  int row = l & 15;
  int kg = l >> 4;

  const h8* A = (const h8*)(f1t + ((size_t)(n0 + row) * CCH) + kg * 8);
  h8 a[8];
#pragma unroll
  for (int ks = 0; ks < 8; ks++) a[ks] = A[ks * 4];

  for (int nt = w * 5; nt < w * 5 + 5; nt++) {
    const half_t* Bb = (nt < 16)
        ? f2l2 + ((size_t)b * 256 + nt * 16) * CCH
        : f2l3 + ((size_t)b * 64 + (nt - 16) * 16) * CCH;
    const h8* Bp = (const h8*)(Bb + (size_t)row * CCH + kg * 8);
    f32x4 acc = {0.f, 0.f, 0.f, 0.f};
#pragma unroll
    for (int ks = 0; ks < 8; ks++)
      acc = __builtin_amdgcn_mfma_f32_16x16x32_f16(a[ks], Bp[ks * 4], acc, 0, 0, 0);
#pragma unroll
    for (int r = 0; r < 4; r++) {
      int q = kg * 4 + r;
      corr[(size_t)(n0 + q) * 320 + nt * 16 + row] = acc[r];
    }
  }
}

// ---------------------------------------------------------------------------
// 16-lane sum via DPP: quad xor1, quad xor2, row_half_mirror, row_mirror.
// ---------------------------------------------------------------------------
__device__ __forceinline__ float dpp_sum16(float x) {
  int v;
  v = __builtin_amdgcn_update_dpp(0, __float_as_int(x), 0xB1, 0xF, 0xF, true);
  x += __int_as_float(v);
  v = __builtin_amdgcn_update_dpp(0, __float_as_int(x), 0x4E, 0xF, 0xF, true);
  x += __int_as_float(v);
  v = __builtin_amdgcn_update_dpp(0, __float_as_int(x), 0x141, 0xF, 0xF, true);
  x += __int_as_float(v);
  v = __builtin_amdgcn_update_dpp(0, __float_as_int(x), 0x140, 0xF, 0xF, true);
  x += __int_as_float(v);
  return x;
}

// ---------------------------------------------------------------------------
// sample8: block = 8 consecutive queries, 8 waves. Wave w: level l = w>>2
// (0/1), query pair p = w&3 -> queries {2p, 2p+1} processed INTERLEAVED in
// the tap loop (4 independent dwordx4 loads in flight per iteration).
// Padded images -> no bounds checks, no branches, incremental offsets.
// Levels 2/3 from corr field gathers. Direct (B,324,H,W) output.
// ---------------------------------------------------------------------------
__global__ __launch_bounds__(512, 8) void sample8(
    const float* __restrict__ coords,
    const half_t* __restrict__ f1t,
    const half_t* __restrict__ f2l0p, const half_t* __restrict__ f2l1p,
    const float* __restrict__ corr,
    float* __restrict__ out) {
  __shared__ float4 f1s4[256];     // 4 KB: 8 q x 256 ch f16 (pre-scaled)
  __shared__ float P[2][8][100];   // 6.4 KB
  __shared__ float wgt[2][8][4];
  __shared__ float cxy[2][8];

  int bid = blockIdx.x;
  int g = ((bid & 7) << 7) | (bid >> 3);   // XCD-contiguous (1024 blocks)
  int n0 = g << 3;
  int b = n0 >> 12;
  int i0 = n0 & 4095;
  int yi = i0 >> 6;
  int x0 = i0 & 63;
  int tid = threadIdx.x;

  if (tid < 256) f1s4[tid] = ((const float4*)(f1t + (size_t)n0 * CCH))[tid];
  if (tid < 16) {
    int q = tid & 7, c = tid >> 3;
    cxy[c][q] = coords[(size_t)(b * 2 + c) * HWHW + i0 + q];
  }
  __syncthreads();

  int w = tid >> 6;
  int l = w >> 2;          // level 0 or 1
  int p = w & 3;           // query pair
  int lane = tid & 63;
  int lg = lane >> 4;
  int l16 = lane & 15;

  int Pl = (l == 0) ? P0 : P1;
  float inv = (l == 0) ? 1.0f : 0.5f;
  const float4* f2b = (l == 0)
      ? (const float4*)f2l0p + ((size_t)b * P0 * P0 + 16 * P0 + 16) * 32 + l16
      : (const float4*)f2l1p + ((size_t)b * P1 * P1 + 16 * P1 + 16) * 32 + l16;
  const h2* f1h = (const h2*)f1s4;

  int q0 = 2 * p, q1 = 2 * p + 1;
  float xl0 = cxy[0][q0] * inv, yl0 = cxy[1][q0] * inv;
  float xl1 = cxy[0][q1] * inv, yl1 = cxy[1][q1] * inv;
  float fx0 = floorf(xl0), fy0 = floorf(yl0);
  float fx1 = floorf(xl1), fy1 = floorf(yl1);
  int ix00 = (int)fx0 - 4, iy00 = (int)fy0 - 4;
  int ix01 = (int)fx1 - 4, iy01 = (int)fy1 - 4;
  if (lane == 0) {
    wgt[l][q0][0] = 1.0f - (xl0 - fx0); wgt[l][q0][1] = xl0 - fx0;
    wgt[l][q0][2] = 1.0f - (yl0 - fy0); wgt[l][q0][3] = yl0 - fy0;
    wgt[l][q1][0] = 1.0f - (xl1 - fx1); wgt[l][q1][1] = xl1 - fx1;
    wgt[l][q1][2] = 1.0f - (yl1 - fy1); wgt[l][q1][3] = yl1 - fy1;
  }

  int fi0 = q0 * 128 + l16 * 4;
  h2 a00 = f1h[fi0], a01 = f1h[fi0 + 1], a02 = f1h[fi0 + 2], a03 = f1h[fi0 + 3];
  h2 a04 = f1h[fi0 + 64], a05 = f1h[fi0 + 65], a06 = f1h[fi0 + 66], a07 = f1h[fi0 + 67];
  int fi1 = q1 * 128 + l16 * 4;
  h2 a10 = f1h[fi1], a11 = f1h[fi1 + 1], a12 = f1h[fi1 + 2], a13 = f1h[fi1 + 3];
  h2 a14 = f1h[fi1 + 64], a15 = f1h[fi1 + 65], a16 = f1h[fi1 + 66], a17 = f1h[fi1 + 67];

  // taps t = it*4 + lg; u = t/10, v = t%10, offsets fully incremental
  int v = lg, t = lg;
  int off0 = (iy00 + lg) * Pl + ix00;    // (iy0+v)*Pl + (ix0+u), u=0
  int off1 = (iy01 + lg) * Pl + ix01;
  const int dP = 4 * Pl;
  const int dW = 1 - 10 * Pl;
  for (int it = 0; it < 25; it++) {
    const float4* tp0 = f2b + (ptrdiff_t)off0 * 32;
    const float4* tp1 = f2b + (ptrdiff_t)off1 * 32;
    float4 A0 = tp0[0];
    float4 B0 = tp0[16];
    float4 A1 = tp1[0];
    float4 B1 = tp1[16];
    const h2* ah0 = (const h2*)&A0;
    const h2* bh0 = (const h2*)&B0;
    const h2* ah1 = (const h2*)&A1;
    const h2* bh1 = (const h2*)&B1;
    float d0 = 0.f, d1 = 0.f;
    d0 = fdot2f(ah0[0], a00, d0); d0 = fdot2f(ah0[1], a01, d0);
    d0 = fdot2f(ah0[2], a02, d0); d0 = fdot2f(ah0[3], a03, d0);
    d0 = fdot2f(bh0[0], a04, d0); d0 = fdot2f(bh0[1], a05, d0);
    d0 = fdot2f(bh0[2], a06, d0); d0 = fdot2f(bh0[3], a07, d0);
    d1 = fdot2f(ah1[0], a10, d1); d1 = fdot2f(ah1[1], a11, d1);
    d1 = fdot2f(ah1[2], a12, d1); d1 = fdot2f(ah1[3], a13, d1);
    d1 = fdot2f(bh1[0], a14, d1); d1 = fdot2f(bh1[1], a15, d1);
    d1 = fdot2f(bh1[2], a16, d1); d1 = fdot2f(bh1[3], a17, d1);
    d0 = dpp_sum16(d0);
    d1 = dpp_sum16(d1);
    if (l16 == 0) { P[l][q0][t] = d0; P[l][q1][t] = d1; }
    t += 4; v += 4;
    off0 += dP; off1 += dP;
    if (v >= 10) { v -= 10; off0 += dW; off1 += dW; }
  }
  __syncthreads();

  // ---- epilogue A: levels 0,1 from P ----
#pragma unroll
  for (int it = 0; it < 3; it++) {
    int kidx = it * 64 + (tid >> 3);
    if (kidx < 162) {
      int lvl = kidx >= 81;
      int k = kidx - 81 * lvl;
      int q = tid & 7;
      int a = k / 9, bb2 = k - a * 9;
      float wx0 = wgt[lvl][q][0], wx1 = wgt[lvl][q][1];
      float wy0 = wgt[lvl][q][2], wy1 = wgt[lvl][q][3];
      const float* Pq = P[lvl][q];
      float val = wy0 * (wx0 * Pq[a * 10 + bb2] + wx1 * Pq[(a + 1) * 10 + bb2])
                + wy1 * (wx0 * Pq[a * 10 + bb2 + 1] + wx1 * Pq[(a + 1) * 10 + bb2 + 1]);
      out[(size_t)(b * KOUT + lvl * 81 + k) * HWHW + (size_t)yi * WW + x0 + q] = val;
    }
  }

  // ---- epilogue B: levels 2,3 via 4-point gathers from corr field ----
#pragma unroll
  for (int it = 0; it < 3; it++) {
    int kidx = it * 64 + (tid >> 3);
    if (kidx < 162) {
      int lvl = 2 + (kidx >= 81);
      int k = kidx - 81 * (kidx >= 81);
      int q = tid & 7;
      float inv2 = (lvl == 2) ? 0.25f : 0.125f;
      int Wl2 = (lvl == 2) ? 16 : 8;
      int base = (lvl == 2) ? 0 : 256;
      float xl = cxy[0][q] * inv2, yl = cxy[1][q] * inv2;
      float fx = floorf(xl), fy = floorf(yl);
      int ix0 = (int)fx - 4, iy0 = (int)fy - 4;
      float wx1 = xl - fx, wx0 = 1.0f - wx1;
      float wy1 = yl - fy, wy0 = 1.0f - wy1;
      const float* cq = corr + (size_t)(n0 + q) * 320 + base;
      int a = k / 9, bb2 = k - a * 9;
      float p00 = 0.f, p10 = 0.f, p01 = 0.f, p11 = 0.f;
      {
        int x = ix0 + a, y = iy0 + bb2;
        if (((unsigned)x < (unsigned)Wl2) & ((unsigned)y < (unsigned)Wl2)) p00 = cq[y * Wl2 + x];
      }
      {
        int x = ix0 + a + 1, y = iy0 + bb2;
        if (((unsigned)x < (unsigned)Wl2) & ((unsigned)y < (unsigned)Wl2)) p10 = cq[y * Wl2 + x];
      }
      {
        int x = ix0 + a, y = iy0 + bb2 + 1;
        if (((unsigned)x < (unsigned)Wl2) & ((unsigned)y < (unsigned)Wl2)) p01 = cq[y * Wl2 + x];
      }
      {
        int x = ix0 + a + 1, y = iy0 + bb2 + 1;
        if (((unsigned)x < (unsigned)Wl2) & ((unsigned)y < (unsigned)Wl2)) p11 = cq[y * Wl2 + x];
      }
      float val = wy0 * (wx0 * p00 + wx1 * p10) + wy1 * (wx0 * p01 + wx1 * p11);
      out[(size_t)(b * KOUT + lvl * 81 + k) * HWHW + (size_t)yi * WW + x0 + q] = val;
    }
  }
}

// ---------------------------------------------------------------------------
extern "C" void kernel_launch(void* const* d_in, const int* in_sizes, int n_in,
                              void* d_out, int out_size, void* d_ws, size_t ws_size,
                              hipStream_t stream) {
  const float* fmap1 = (const float*)d_in[0];
  const float* fmap2 = (const float*)d_in[1];
  const float* coords = (const float*)d_in[2];
  float* out = (float*)d_out;

  char* ws = (char*)d_ws;
  half_t* f1t   = (half_t*)(ws);                   // 4 MB  @ 0
  half_t* f2l0p = (half_t*)(ws + 4194304);         // 9.44 MB (B,96,96,C) padded
  half_t* f2l1p = (half_t*)(ws + 13631488);        // 4.19 MB (B,64,64,C) padded
  half_t* f2l2  = (half_t*)(ws + 17825792);        // 256 KB (B,16,16,C)
  half_t* f2l3  = (half_t*)(ws + 18087936);        // 64 KB  (B,8,8,C)
  float*  corr  = (float*)(ws + 18153472);         // 10.5 MB (B*HW, 320) fp32

  // zero padded l0+l1 region (contiguous: 13,631,488 B starting at f2l0p)
  int nz = 13631488 / 16;
  zero_pads<<<nz / 256, 256, 0, stream>>>((float4*)f2l0p, nz);

  dim3 tb(32, 8, 1);
  dim3 tg(HWHW / 32, CCH / 32, 4);
  transpose_cl<<<tg, tb, 0, stream>>>(fmap1, fmap2, f1t, f2l0p);

  int npool = B2 * (32 * 32 + 16 * 16 + 8 * 8) * 128;
  pool_all<<<(npool + 255) / 256, 256, 0, stream>>>(
      (const h2*)f2l0p, (h2*)f2l1p, (h2*)f2l2, (h2*)f2l3);

  corr23_k<<<512, 256, 0, stream>>>(f1t, f2l2, f2l3, corr);

  sample8<<<1024, 512, 0, stream>>>(coords, f1t, f2l0p, f2l1p, corr, out);
}